// Round 17
// baseline (970.466 us; speedup 1.0000x reference)
//
// Round 17: ZERO in-loop dequant. Pass-1 dequants q->fp16 directly into fragment-ordered
// Whf (pqt layout, 16B payloads) so B-fragments are contiguous 1KB wave loads global->reg
// (double-buffered in regs, 2-tile unrolled body). A unchanged: dbuf LDS 32KB gload_lds+XOR.
// 128x256 tile, 4 waves, 2 blocks/CU, XCD n-fastest, NT stores. Kernel is issue-bound ->
// cutting ~250 VALU/tile/wave is the lever.
#include <hip/hip_runtime.h>
#include <stdint.h>

#define TOKENS 8192
#define KDIM   4096
#define NDIM   11008
#define BM 128
#define BN 256
#define BK 64
#define KTILES (KDIM / BK)            // 64
#define WF_BYTES 90177536ull          // 11008*4096*2 (fragment-ordered fp16 W)
#define XH_BYTES 67108864ull          // 8192*4096*2
#define WS_FULL  (WF_BYTES + XH_BYTES)

typedef _Float16 f16x8 __attribute__((ext_vector_type(8)));
typedef float    f32x4 __attribute__((ext_vector_type(4)));

typedef const __attribute__((address_space(1))) unsigned int* gptr_t;
typedef __attribute__((address_space(3))) unsigned int* lptr_t;

// ---- pass 1a: fused dequant q -> fp16 in FRAGMENT ORDER.
// Unit g = (n-block np, k-octet o, col c): f16x8 slot g = np*8192 + o*16 + c holds
// W[n=np*16+c][k=o*8 .. o*8+7]. Same rounding chain as the absmax-0.125 path.
__global__ __launch_bounds__(256) void dequant_wf(const int* __restrict__ q,
                                                  const float* __restrict__ Sc,
                                                  const float* __restrict__ Zp,
                                                  f16x8* __restrict__ wf) {
    const unsigned int g = blockIdx.x * 256 + threadIdx.x;   // 0..5636095
    const int c  = g & 15;
    const int o  = (g >> 4) & 511;
    const int np = g >> 13;
    const int n  = np * 16 + c;
    const int grp = o >> 4;                                   // k-group (128 wide)
    const float sf = Sc[(size_t)grp * NDIM + n];
    const float zf = Zp[(size_t)grp * NDIM + n];
    const int4* p = (const int4*)(q + (size_t)n * KDIM + o * 8);
    const int4 a = p[0], b = p[1];
    const int qv[8] = {a.x, a.y, a.z, a.w, b.x, b.y, b.z, b.w};
    f16x8 w;
#pragma unroll
    for (int j = 0; j < 8; ++j) w[j] = (_Float16)((float)qv[j] * sf + zf);
    wf[g] = w;
}

// ---- pass 1b: x fp32 -> fp16 (exact) ----
__global__ __launch_bounds__(256) void cvt_x(const float* __restrict__ x,
                                             _Float16* __restrict__ xh) {
    const size_t idx = (size_t)(blockIdx.x * 256 + threadIdx.x) * 8;
    const float4* p = (const float4*)(x + idx);
    const float4 a = p[0], b = p[1];
    f16x8 o;
    o[0] = (_Float16)a.x; o[1] = (_Float16)a.y; o[2] = (_Float16)a.z; o[3] = (_Float16)a.w;
    o[4] = (_Float16)b.x; o[5] = (_Float16)b.y; o[6] = (_Float16)b.z; o[7] = (_Float16)b.w;
    *(f16x8*)(xh + idx) = o;
}

// ---- pass 2: 128x256 4-wave GEMM; A in dbuf LDS, B direct global->reg (dbuf) ----
__global__ __launch_bounds__(256, 2)
void wq_gemm_wf(const _Float16* __restrict__ Xh, const f16x8* __restrict__ Wf,
                const float* __restrict__ Bi, float* __restrict__ Out)
{
    __shared__ __align__(16) _Float16 As[2][BM * BK];   // 2 x 16 KB

    const int t    = threadIdx.x;
    const int lane = t & 63;
    const int wid  = t >> 6;        // 0..3
    const int wnc  = wid;           // wave owns cols wnc*64..+64; all share 128 m-rows

    // XCD-bijective, n-fastest (2752 = 8*344)
    const unsigned int bid = blockIdx.x;
    const unsigned int wg  = (bid & 7u) * 344u + (bid >> 3);
    const int m0 = (int)(wg / 43u) * BM;
    const int n0 = (int)(wg % 43u) * BN;

    // A staging (proven conflict-free): gload_lds, linear LDS dest, pre-XOR'd source:
    // phys blk = logical ^ (row&7). Issue i covers rows i*32 + wid*8 + (lane>>3).
    const int alr = lane >> 3;
    const int alb = lane & 7;
    const _Float16* aSrc = Xh + (size_t)(m0 + wid * 8 + alr) * KDIM + ((alb ^ alr) << 3);

    // fragment read map
    const int fr = lane & 15;
    const int fq = lane >> 4;       // 0..3
    const int fx = fr & 7;

    // B per-lane source: slot (nb+j)*8192 + (kt*8 + kh*4 + fq)*16 + fr
    // wave covers 64 consecutive f16x8 slots (1KB) per (j,kh) -> fully coalesced.
    const int nb = (n0 + wnc * 64) >> 4;
    const f16x8* qb8 = Wf + (size_t)nb * 8192 + fq * 16 + fr;

    f32x4 acc[8][4];
#pragma unroll
    for (int i = 0; i < 8; ++i)
#pragma unroll
        for (int j = 0; j < 4; ++j)
            acc[i][j] = f32x4{0.f, 0.f, 0.f, 0.f};

#define A_STAGE(buf, ktv) do {                                                        \
    _Pragma("unroll")                                                                 \
    for (int i_ = 0; i_ < 4; ++i_)                                                    \
        __builtin_amdgcn_global_load_lds(                                             \
            (gptr_t)(const void*)(aSrc + (size_t)i_ * 32 * KDIM + (ktv) * BK),        \
            (lptr_t)(void*)(&As[buf][i_ * 2048 + wid * 512]), 16, 0, 0);              \
} while (0)

// load one tile's 8 B-fragments into named regs (VMEM, zero VALU beyond addressing)
#define B_LOAD(B0, B1, ktv) do {                                                      \
    _Pragma("unroll")                                                                 \
    for (int j_ = 0; j_ < 4; ++j_) {                                                  \
        B0[j_] = qb8[(size_t)j_ * 8192 + (ktv) * 128];                                \
        B1[j_] = qb8[(size_t)j_ * 8192 + (ktv) * 128 + 64];                           \
    }                                                                                 \
} while (0)

#define CLUSTER(p_, KH, bfv) do {                                                     \
    f16x8 af0_, af1_;                                                                 \
    af0_ = *(const f16x8*)&As[cur_][(((p_) * 2 + 0) * 16 + fr) * 64 +                 \
                                    ((((KH) << 2) | fq) ^ fx) * 8];                   \
    af1_ = *(const f16x8*)&As[cur_][(((p_) * 2 + 1) * 16 + fr) * 64 +                 \
                                    ((((KH) << 2) | fq) ^ fx) * 8];                   \
    _Pragma("unroll")                                                                 \
    for (int j_ = 0; j_ < 4; ++j_) {                                                  \
        acc[(p_) * 2 + 0][j_] = __builtin_amdgcn_mfma_f32_16x16x32_f16(               \
            af0_, bfv[j_], acc[(p_) * 2 + 0][j_], 0, 0, 0);                           \
        acc[(p_) * 2 + 1][j_] = __builtin_amdgcn_mfma_f32_16x16x32_f16(               \
            af1_, bfv[j_], acc[(p_) * 2 + 1][j_], 0, 0, 0);                           \
    }                                                                                 \
} while (0)

// one K-tile: stage next A, load next B (into LDA set), compute with USE set, barrier
#define ITER(CUR, U0, U1, L0, L1, KT) do {                                            \
    const int cur_ = (CUR);                                                           \
    if ((KT) + 1 < KTILES) {                                                          \
        A_STAGE(cur_ ^ 1, (KT) + 1);                                                  \
        B_LOAD(L0, L1, (KT) + 1);                                                     \
    }                                                                                 \
    CLUSTER(0, 0, U0); CLUSTER(1, 0, U0); CLUSTER(2, 0, U0); CLUSTER(3, 0, U0);       \
    CLUSTER(0, 1, U1); CLUSTER(1, 1, U1); CLUSTER(2, 1, U1); CLUSTER(3, 1, U1);       \
    __syncthreads();                                                                  \
} while (0)

    f16x8 bA0[4], bA1[4], bB0[4], bB1[4];

    // ---- prologue: A(0) DMA + B(0) loads ----
    A_STAGE(0, 0);
    B_LOAD(bA0, bA1, 0);
    __syncthreads();                      // A(0) landed; bA waits inserted by compiler

    // ---- main loop: 2-tile unrolled (no register copies; KTILES=64 even) ----
    for (int kt = 0; kt < KTILES; kt += 2) {
        ITER(0, bA0, bA1, bB0, bB1, kt);
        ITER(1, bB0, bB1, bA0, bA1, kt + 1);
    }
#undef A_STAGE
#undef B_LOAD
#undef CLUSTER
#undef ITER

    // epilogue: C/D map col=lane&15, row=(lane>>4)*4+reg; out = f32(f16(acc)+f16(bias))
#pragma unroll
    for (int j = 0; j < 4; ++j) {
        const int n = n0 + wnc * 64 + j * 16 + fr;
        const _Float16 bv = (_Float16)Bi[n];
#pragma unroll
        for (int im = 0; im < 8; ++im) {
            const int mbase = m0 + im * 16 + fq * 4;
#pragma unroll
            for (int r = 0; r < 4; ++r) {
                const _Float16 h = (_Float16)acc[im][j][r] + bv;
                __builtin_nontemporal_store((float)h, &Out[(size_t)(mbase + r) * NDIM + n]);
            }
        }
    }
}

// ---------------- fallback: round-5 direct kernel (no workspace) ----------------
__global__ __launch_bounds__(256, 2)
void wq_gemm_direct(const float* __restrict__ X,  const int* __restrict__ Qw,
                    const float* __restrict__ Sc, const float* __restrict__ Zp,
                    const float* __restrict__ Bi, float* __restrict__ Out)
{
    __shared__ __align__(16) _Float16 As[128 * 32];
    __shared__ __align__(16) _Float16 Bs[128 * 32];
    const int t = threadIdx.x, lane = t & 63, wid = t >> 6;
    const int wr = wid >> 1, wc = wid & 1;
    const int n0 = blockIdx.x * 128, m0 = blockIdx.y * 128;
    const int srow = t >> 1, shalf = (t & 1) << 4;
    const float* xsrc = X + (size_t)(m0 + srow) * KDIM + shalf;
    const int*   qsrc = Qw + (size_t)(n0 + srow) * KDIM + shalf;
    const float* scp = Sc + n0 + srow;
    const float* zpp = Zp + n0 + srow;
    _Float16* adst = As + srow * 32 + shalf;
    _Float16* bdst = Bs + srow * 32 + shalf;
    const int fr = lane & 15, fq = lane >> 4;
    const _Float16* ard = As + (wr * 64 + fr) * 32 + fq * 8;
    const _Float16* brd = Bs + (wc * 64 + fr) * 32 + fq * 8;
    f32x4 acc[4][4];
#pragma unroll
    for (int i = 0; i < 4; ++i)
#pragma unroll
        for (int j = 0; j < 4; ++j) acc[i][j] = f32x4{0.f, 0.f, 0.f, 0.f};
    for (int kt = 0; kt < KDIM / 32; ++kt) {
        const int k0 = kt * 32;
        const float4* xp = (const float4*)(xsrc + k0);
        const float4 x0 = xp[0], x1 = xp[1], x2 = xp[2], x3 = xp[3];
        const float xv[16] = {x0.x, x0.y, x0.z, x0.w, x1.x, x1.y, x1.z, x1.w,
                              x2.x, x2.y, x2.z, x2.w, x3.x, x3.y, x3.z, x3.w};
        f16x8 a0, a1;
#pragma unroll
        for (int j = 0; j < 8; ++j) { a0[j] = (_Float16)xv[j]; a1[j] = (_Float16)xv[j + 8]; }
        const int g = k0 >> 7;
        const float sf = scp[(size_t)g * NDIM];
        const float zf = zpp[(size_t)g * NDIM];
        const int4* qp = (const int4*)(qsrc + k0);
        const int4 q0 = qp[0], q1 = qp[1], q2 = qp[2], q3 = qp[3];
        const int qv[16] = {q0.x, q0.y, q0.z, q0.w, q1.x, q1.y, q1.z, q1.w,
                            q2.x, q2.y, q2.z, q2.w, q3.x, q3.y, q3.z, q3.w};
        f16x8 w0, w1;
#pragma unroll
        for (int j = 0; j < 8; ++j) {
            w0[j] = (_Float16)((float)qv[j]     * sf + zf);
            w1[j] = (_Float16)((float)qv[j + 8] * sf + zf);
        }
        *(f16x8*)adst = a0; *(f16x8*)(adst + 8) = a1;
        *(f16x8*)bdst = w0; *(f16x8*)(bdst + 8) = w1;
        __syncthreads();
        f16x8 a[4], b[4];
#pragma unroll
        for (int i = 0; i < 4; ++i) a[i] = *(const f16x8*)(ard + i * 16 * 32);
#pragma unroll
        for (int j = 0; j < 4; ++j) b[j] = *(const f16x8*)(brd + j * 16 * 32);
#pragma unroll
        for (int i = 0; i < 4; ++i)
#pragma unroll
            for (int j = 0; j < 4; ++j)
                acc[i][j] = __builtin_amdgcn_mfma_f32_16x16x32_f16(a[i], b[j], acc[i][j], 0, 0, 0);
        __syncthreads();
    }
#pragma unroll
    for (int j = 0; j < 4; ++j) {
        const int n = n0 + wc * 64 + j * 16 + fr;
        const _Float16 bv = (_Float16)Bi[n];
#pragma unroll
        for (int i = 0; i < 4; ++i) {
            const int mbase = m0 + wr * 64 + i * 16 + fq * 4;
#pragma unroll
            for (int r = 0; r < 4; ++r) {
                const _Float16 h = (_Float16)acc[i][j][r] + bv;
                Out[(size_t)(mbase + r) * NDIM + n] = (float)h;
            }
        }
    }
}

extern "C" void kernel_launch(void* const* d_in, const int* in_sizes, int n_in,
                              void* d_out, int out_size, void* d_ws, size_t ws_size,
                              hipStream_t stream) {
    const float* x  = nullptr;
    const int*   q  = nullptr;
    const float* sc = nullptr;
    const float* zp = nullptr;
    const float* bi = nullptr;
    for (int i = 0; i < n_in; ++i) {
        switch (in_sizes[i]) {
            case 33554432: x = (const float*)d_in[i]; break;
            case 45088768: q = (const int*)d_in[i]; break;
            case 352256:   if (!sc) sc = (const float*)d_in[i];
                           else     zp = (const float*)d_in[i];
                           break;
            case 11008:    bi = (const float*)d_in[i]; break;
            default: break;
        }
    }
    if (!x || !q || !sc || !zp || !bi) {
        x  = (const float*)d_in[0];
        q  = (const int*)d_in[1];
        sc = (const float*)d_in[2];
        zp = (const float*)d_in[3];
        bi = (const float*)d_in[4];
    }
    float* out = (float*)d_out;

    if (ws_size >= (size_t)WS_FULL) {
        f16x8*    wf = (f16x8*)d_ws;
        _Float16* xh = (_Float16*)((char*)d_ws + WF_BYTES);
        dequant_wf<<<5636096 / 256, 256, 0, stream>>>(q, sc, zp, wf);
        cvt_x<<<33554432 / 8 / 256, 256, 0, stream>>>(x, xh);
        wq_gemm_wf<<<(TOKENS / BM) * (NDIM / BN), 256, 0, stream>>>(xh, wf, bi, out);
    } else {
        dim3 grid(NDIM / 128, TOKENS / 128);
        wq_gemm_direct<<<grid, dim3(256), 0, stream>>>(x, q, sc, zp, bi, out);
    }
}

// Round 18
// 789.457 us; speedup vs baseline: 1.2293x; 1.2293x over previous
//
// Round 18: R15 data plan (packed-q reg-dequant, A-only dbuf LDS 32KB) + 32x32x16 MFMA
// (half the MFMA instrs, faster pipe: floor 356->296us) + 2-tile unroll (no reg copies,
// halved s/z loads). B stays 4-bit in memory (L3-resident; R17 lesson). 128x256 tile,
// 4 waves, 2 blocks/CU, XCD n-fastest, NT stores.
#include <hip/hip_runtime.h>
#include <stdint.h>

#define TOKENS 8192
#define KDIM   4096
#define NDIM   11008
#define BM 128
#define BN 256
#define BK 64
#define KTILES (KDIM / BK)          // 64
#define PQ_BYTES (45088768u/8u*4u)  // 22544384
#define XH_BYTES (33554432ull*2ull) // 67108864
#define WS_PACKED ((size_t)PQ_BYTES + XH_BYTES)

typedef _Float16 f16x8  __attribute__((ext_vector_type(8)));
typedef _Float16 f16x2  __attribute__((ext_vector_type(2)));
typedef float    f32x16 __attribute__((ext_vector_type(16)));

typedef const __attribute__((address_space(1))) unsigned int* gptr_t;
typedef __attribute__((address_space(3))) unsigned int* lptr_t;

// ---- pass 1a: TRANSPOSED permuted pack (UNCHANGED, proven). dword(col n, k-octet o) at
// (n>>4)*8192 + o*16 + (n&15); nibbles [k0,k2,k4,k6,k1,k3,k5,k7] so
// ((d>>4p)&0x000F000F)|0x64006400 = fp16 pair (1024+k_{2p}, 1024+k_{2p+1}).
__global__ __launch_bounds__(256) void pack_qt(const int* __restrict__ q,
                                               unsigned int* __restrict__ pqt) {
    const unsigned int g = blockIdx.x * 256 + threadIdx.x;   // 0..5636095
    const int c  = g & 15;
    const int o  = (g >> 4) & 511;
    const int np = g >> 13;
    const int n  = np * 16 + c;
    const int4* p = (const int4*)(q + (size_t)n * KDIM + o * 8);
    const int4 a = p[0], b = p[1];
    unsigned int w = (unsigned int)(a.x & 15)
                   | ((unsigned int)(a.z & 15) << 4)
                   | ((unsigned int)(b.x & 15) << 8)
                   | ((unsigned int)(b.z & 15) << 12)
                   | ((unsigned int)(a.y & 15) << 16)
                   | ((unsigned int)(a.w & 15) << 20)
                   | ((unsigned int)(b.y & 15) << 24)
                   | ((unsigned int)(b.w & 15) << 28);
    pqt[g] = w;
}

// ---- pass 1b: x fp32 -> fp16 (exact) ----
__global__ __launch_bounds__(256) void cvt_x(const float* __restrict__ x,
                                             _Float16* __restrict__ xh) {
    const size_t idx = (size_t)(blockIdx.x * 256 + threadIdx.x) * 8;
    const float4* p = (const float4*)(x + idx);
    const float4 a = p[0], b = p[1];
    f16x8 o;
    o[0] = (_Float16)a.x; o[1] = (_Float16)a.y; o[2] = (_Float16)a.z; o[3] = (_Float16)a.w;
    o[4] = (_Float16)b.x; o[5] = (_Float16)b.y; o[6] = (_Float16)b.z; o[7] = (_Float16)b.w;
    *(f16x8*)(xh + idx) = o;
}

// ---- pass 2: 128x256 4-wave GEMM, 32x32x16 MFMA, A in dbuf LDS, reg-B dequant ----
__global__ __launch_bounds__(256, 2)
void wq_gemm_32(const _Float16* __restrict__ Xh, const unsigned int* __restrict__ Pqt,
                const float* __restrict__ Sc, const float* __restrict__ Zp,
                const float* __restrict__ Bi, float* __restrict__ Out)
{
    __shared__ __align__(16) _Float16 As[2][BM * BK];   // 2 x 16 KB

    const int t    = threadIdx.x;
    const int lane = t & 63;
    const int wid  = t >> 6;        // 0..3
    const int wnc  = wid;           // wave owns cols wnc*64..+64; all share 128 m-rows

    // XCD-bijective, n-fastest (2752 = 8*344)
    const unsigned int bid = blockIdx.x;
    const unsigned int wg  = (bid & 7u) * 344u + (bid >> 3);
    const int m0 = (int)(wg / 43u) * BM;
    const int n0 = (int)(wg % 43u) * BN;

    // A staging (proven): gload_lds, linear LDS dest, pre-XOR'd source (phys blk =
    // logical ^ (row&7)). Issue i covers rows i*32 + wid*8 + (lane>>3).
    const int alr = lane >> 3;
    const int alb = lane & 7;
    const _Float16* aSrc = Xh + (size_t)(m0 + wid * 8 + alr) * KDIM + ((alb ^ alr) << 3);

    // 32x32x16 fragment lane maps: row/col = lane&31, k-octet = lane>>5
    const int l31  = lane & 31;
    const int l15  = lane & 15;
    const int npo  = (lane >> 4) & 1;   // which 16-col pqt block within the 32-col tile
    const int koff = lane >> 5;         // k-octet half
    const int lx7  = l31 & 7;           // A-LDS XOR key

    // B per-lane source: dword(nt,ks,kt) = qb[nt*16384 + (kt*8 + ks*2)*16]
    const int nb = (n0 + wnc * 64) >> 4;
    const unsigned int* qb = Pqt + (size_t)(nb + npo) * 8192 + koff * 16 + l15;

    // s/z per-lane columns: n = n0 + wnc*64 + nt*32 + l31
    const float* scol = Sc + n0 + wnc * 64 + l31;   // + g*NDIM + nt*32
    const float* zcol = Zp + n0 + wnc * 64 + l31;

    f32x16 acc[4][2];
#pragma unroll
    for (int mt = 0; mt < 4; ++mt)
#pragma unroll
        for (int nt = 0; nt < 2; ++nt)
#pragma unroll
            for (int r = 0; r < 16; ++r) acc[mt][nt][r] = 0.f;

    const f16x2 k1024 = {(_Float16)1024.0f, (_Float16)1024.0f};

#define A_STAGE(buf, ktv) do {                                                        \
    _Pragma("unroll")                                                                 \
    for (int i_ = 0; i_ < 4; ++i_)                                                    \
        __builtin_amdgcn_global_load_lds(                                             \
            (gptr_t)(const void*)(aSrc + (size_t)i_ * 32 * KDIM + (ktv) * BK),        \
            (lptr_t)(void*)(&As[buf][i_ * 2048 + wid * 512]), 16, 0, 0);              \
} while (0)

#define B_LOAD(Q, ktv) do {                                                           \
    _Pragma("unroll")                                                                 \
    for (int nt_ = 0; nt_ < 2; ++nt_)                                                 \
        _Pragma("unroll")                                                             \
        for (int ks_ = 0; ks_ < 4; ++ks_)                                             \
            Q[nt_ * 4 + ks_] = qb[(size_t)nt_ * 16384 + ((ktv) * 8 + ks_ * 2) * 16];  \
} while (0)

#define DEQ_REG(dst, dw, s2v, z2v) do {                                               \
    unsigned int o_[4];                                                               \
    _Pragma("unroll")                                                                 \
    for (int p_ = 0; p_ < 4; ++p_) {                                                  \
        unsigned int u_ = (((dw) >> (4 * p_)) & 0x000F000Fu) | 0x64006400u;           \
        f16x2 h_ = __builtin_bit_cast(f16x2, u_);                                     \
        f16x2 q_ = h_ - k1024;                                                        \
        f16x2 w_ = q_ * (s2v) + (z2v);                                                \
        o_[p_] = __builtin_bit_cast(unsigned int, w_);                                \
    }                                                                                 \
    (dst) = __builtin_bit_cast(f16x8, uint4{o_[0], o_[1], o_[2], o_[3]});             \
} while (0)

// one K-tile: buf = KT&1; stage A(KT+1)->buf^1; load QL(KT+1); DEQ QU; 32 MFMA; barrier
#define ITER(QU, QL, S2, Z2, KT, LOADNEXT) do {                                       \
    const int buf_ = (KT) & 1;                                                        \
    if (LOADNEXT) { A_STAGE(buf_ ^ 1, (KT) + 1); B_LOAD(QL, (KT) + 1); }              \
    f16x8 bf_[8];                                                                     \
    _Pragma("unroll")                                                                 \
    for (int nt_ = 0; nt_ < 2; ++nt_)                                                 \
        _Pragma("unroll")                                                             \
        for (int ks_ = 0; ks_ < 4; ++ks_)                                             \
            DEQ_REG(bf_[nt_ * 4 + ks_], QU[nt_ * 4 + ks_], S2[nt_], Z2[nt_]);         \
    _Pragma("unroll")                                                                 \
    for (int mt_ = 0; mt_ < 4; ++mt_) {                                               \
        f16x8 af_[4];                                                                 \
        _Pragma("unroll")                                                             \
        for (int ks_ = 0; ks_ < 4; ++ks_)                                             \
            af_[ks_] = *(const f16x8*)&As[buf_][(mt_ * 32 + l31) * 64 +               \
                                               ((ks_ * 2 + koff) ^ lx7) * 8];         \
        _Pragma("unroll")                                                             \
        for (int ks_ = 0; ks_ < 4; ++ks_)                                             \
            _Pragma("unroll")                                                         \
            for (int nt_ = 0; nt_ < 2; ++nt_)                                         \
                acc[mt_][nt_] = __builtin_amdgcn_mfma_f32_32x32x16_f16(               \
                    af_[ks_], bf_[nt_ * 4 + ks_], acc[mt_][nt_], 0, 0, 0);            \
    }                                                                                 \
    __syncthreads();                                                                  \
} while (0)

    unsigned int qa[8], qb2[8];
    f16x2 s2c[2], z2c[2], s2n[2], z2n[2];

    // ---- prologue: A(0) DMA; q(0); s/z(group 0) ----
    A_STAGE(0, 0);
    B_LOAD(qa, 0);
#pragma unroll
    for (int nt = 0; nt < 2; ++nt) {
        const float s_ = scol[nt * 32];
        const float z_ = zcol[nt * 32];
        s2c[nt] = f16x2{(_Float16)s_, (_Float16)s_};
        z2c[nt] = f16x2{(_Float16)z_, (_Float16)z_};
        s2n[nt] = s2c[nt]; z2n[nt] = z2c[nt];
    }
    __syncthreads();                      // A(0)+qa landed

    // ---- main loop: pairs share a scale group (g = kt>>1) ----
    for (int kt = 0; kt < KTILES; kt += 2) {
        // even tile: uses qa, loads qb2(kt+1)
        ITER(qa, qb2, s2c, z2c, kt, 1);
        // odd tile: uses qb2, loads qa(kt+2) + s/z for next group
        {
            const bool more = (kt + 2 < KTILES);
            if (more) {
                const int gn = (kt + 2) >> 1;
#pragma unroll
                for (int nt = 0; nt < 2; ++nt) {
                    const float s_ = scol[(size_t)gn * NDIM + nt * 32];
                    const float z_ = zcol[(size_t)gn * NDIM + nt * 32];
                    s2n[nt] = f16x2{(_Float16)s_, (_Float16)s_};
                    z2n[nt] = f16x2{(_Float16)z_, (_Float16)z_};
                }
            }
            ITER(qb2, qa, s2c, z2c, kt + 1, more);
#pragma unroll
            for (int nt = 0; nt < 2; ++nt) { s2c[nt] = s2n[nt]; z2c[nt] = z2n[nt]; }
        }
    }
#undef A_STAGE
#undef B_LOAD
#undef DEQ_REG
#undef ITER

    // epilogue: 32x32 C/D map col=lane&31, row=(r&3)+8*(r>>2)+4*(lane>>5) (m74/m101);
    // out = f32(f16(acc)+f16(bias)); NT stores.
#pragma unroll
    for (int nt = 0; nt < 2; ++nt) {
        const int n = n0 + wnc * 64 + nt * 32 + l31;
        const _Float16 bv = (_Float16)Bi[n];
#pragma unroll
        for (int mt = 0; mt < 4; ++mt) {
#pragma unroll
            for (int r = 0; r < 16; ++r) {
                const int m = m0 + mt * 32 + (r & 3) + 8 * (r >> 2) + 4 * koff;
                const _Float16 h = (_Float16)acc[mt][nt][r] + bv;
                __builtin_nontemporal_store((float)h, &Out[(size_t)m * NDIM + n]);
            }
        }
    }
}

// ---------------- fallback: round-5 direct kernel (no workspace) ----------------
typedef float f32x4 __attribute__((ext_vector_type(4)));
__global__ __launch_bounds__(256, 2)
void wq_gemm_direct(const float* __restrict__ X,  const int* __restrict__ Qw,
                    const float* __restrict__ Sc, const float* __restrict__ Zp,
                    const float* __restrict__ Bi, float* __restrict__ Out)
{
    __shared__ __align__(16) _Float16 As[128 * 32];
    __shared__ __align__(16) _Float16 Bs[128 * 32];
    const int t = threadIdx.x, lane = t & 63, wid = t >> 6;
    const int wr = wid >> 1, wc = wid & 1;
    const int n0 = blockIdx.x * 128, m0 = blockIdx.y * 128;
    const int srow = t >> 1, shalf = (t & 1) << 4;
    const float* xsrc = X + (size_t)(m0 + srow) * KDIM + shalf;
    const int*   qsrc = Qw + (size_t)(n0 + srow) * KDIM + shalf;
    const float* scp = Sc + n0 + srow;
    const float* zpp = Zp + n0 + srow;
    _Float16* adst = As + srow * 32 + shalf;
    _Float16* bdst = Bs + srow * 32 + shalf;
    const int fr = lane & 15, fq = lane >> 4;
    const _Float16* ard = As + (wr * 64 + fr) * 32 + fq * 8;
    const _Float16* brd = Bs + (wc * 64 + fr) * 32 + fq * 8;
    f32x4 acc[4][4];
#pragma unroll
    for (int i = 0; i < 4; ++i)
#pragma unroll
        for (int j = 0; j < 4; ++j) acc[i][j] = f32x4{0.f, 0.f, 0.f, 0.f};
    for (int kt = 0; kt < KDIM / 32; ++kt) {
        const int k0 = kt * 32;
        const float4* xp = (const float4*)(xsrc + k0);
        const float4 x0 = xp[0], x1 = xp[1], x2 = xp[2], x3 = xp[3];
        const float xv[16] = {x0.x, x0.y, x0.z, x0.w, x1.x, x1.y, x1.z, x1.w,
                              x2.x, x2.y, x2.z, x2.w, x3.x, x3.y, x3.z, x3.w};
        f16x8 a0, a1;
#pragma unroll
        for (int j = 0; j < 8; ++j) { a0[j] = (_Float16)xv[j]; a1[j] = (_Float16)xv[j + 8]; }
        const int g = k0 >> 7;
        const float sf = scp[(size_t)g * NDIM];
        const float zf = zpp[(size_t)g * NDIM];
        const int4* qp = (const int4*)(qsrc + k0);
        const int4 q0 = qp[0], q1 = qp[1], q2 = qp[2], q3 = qp[3];
        const int qv[16] = {q0.x, q0.y, q0.z, q0.w, q1.x, q1.y, q1.z, q1.w,
                            q2.x, q2.y, q2.z, q2.w, q3.x, q3.y, q3.z, q3.w};
        f16x8 w0, w1;
#pragma unroll
        for (int j = 0; j < 8; ++j) {
            w0[j] = (_Float16)((float)qv[j]     * sf + zf);
            w1[j] = (_Float16)((float)qv[j + 8] * sf + zf);
        }
        *(f16x8*)adst = a0; *(f16x8*)(adst + 8) = a1;
        *(f16x8*)bdst = w0; *(f16x8*)(bdst + 8) = w1;
        __syncthreads();
        f16x8 a[4], b[4];
#pragma unroll
        for (int i = 0; i < 4; ++i) a[i] = *(const f16x8*)(ard + i * 16 * 32);
#pragma unroll
        for (int j = 0; j < 4; ++j) b[j] = *(const f16x8*)(brd + j * 16 * 32);
#pragma unroll
        for (int i = 0; i < 4; ++i)
#pragma unroll
            for (int j = 0; j < 4; ++j)
                acc[i][j] = __builtin_amdgcn_mfma_f32_16x16x32_f16(a[i], b[j], acc[i][j], 0, 0, 0);
        __syncthreads();
    }
#pragma unroll
    for (int j = 0; j < 4; ++j) {
        const int n = n0 + wc * 64 + j * 16 + fr;
        const _Float16 bv = (_Float16)Bi[n];
#pragma unroll
        for (int i = 0; i < 4; ++i) {
            const int mbase = m0 + wr * 64 + i * 16 + fq * 4;
#pragma unroll
            for (int r = 0; r < 4; ++r) {
                const _Float16 h = (_Float16)acc[i][j][r] + bv;
                Out[(size_t)(mbase + r) * NDIM + n] = (float)h;
            }
        }
    }
}

extern "C" void kernel_launch(void* const* d_in, const int* in_sizes, int n_in,
                              void* d_out, int out_size, void* d_ws, size_t ws_size,
                              hipStream_t stream) {
    const float* x  = nullptr;
    const int*   q  = nullptr;
    const float* sc = nullptr;
    const float* zp = nullptr;
    const float* bi = nullptr;
    for (int i = 0; i < n_in; ++i) {
        switch (in_sizes[i]) {
            case 33554432: x = (const float*)d_in[i]; break;
            case 45088768: q = (const int*)d_in[i]; break;
            case 352256:   if (!sc) sc = (const float*)d_in[i];
                           else     zp = (const float*)d_in[i];
                           break;
            case 11008:    bi = (const float*)d_in[i]; break;
            default: break;
        }
    }
    if (!x || !q || !sc || !zp || !bi) {
        x  = (const float*)d_in[0];
        q  = (const int*)d_in[1];
        sc = (const float*)d_in[2];
        zp = (const float*)d_in[3];
        bi = (const float*)d_in[4];
    }
    float* out = (float*)d_out;

    if (ws_size >= WS_PACKED) {
        unsigned int* pqt = (unsigned int*)d_ws;
        _Float16*     xh  = (_Float16*)((char*)d_ws + PQ_BYTES);
        pack_qt<<<5636096 / 256, 256, 0, stream>>>(q, pqt);
        cvt_x<<<33554432 / 8 / 256, 256, 0, stream>>>(x, xh);
        wq_gemm_32<<<(TOKENS / BM) * (NDIM / BN), 256, 0, stream>>>(xh, pqt, sc, zp, bi, out);
    } else {
        dim3 grid(NDIM / 128, TOKENS / 128);
        wq_gemm_direct<<<grid, dim3(256), 0, stream>>>(x, q, sc, zp, bi, out);
    }
}